// Round 1
// baseline (906.160 us; speedup 1.0000x reference)
//
#include <hip/hip_runtime.h>

#define Bb   2
#define Cc   256
#define Nn   100000
#define Hh   256
#define Ww   256
#define HWp  65536
#define TOK  64
#define NBLK ((Nn + TOK - 1) / TOK)   // 1563

// ---------------- Kernel 1: LayerNorm(channel) + scatter-add ----------------
__global__ __launch_bounds__(256) void ln_scatter_kernel(
    const float* __restrict__ tokens, const int* __restrict__ fidx,
    const float* __restrict__ lnw, const float* __restrict__ lnb,
    float* __restrict__ grid, float* __restrict__ cnt)
{
    __shared__ float xs[Cc][TOK + 1];      // padded: bank = (c+t)%32, conflict-free
    __shared__ float ps[4][TOK];
    __shared__ float pss[4][TOK];
    __shared__ float mu_s[TOK], rs_s[TOK];
    __shared__ int   fid_s[TOK];

    const int tid = threadIdx.x;
    const int bt  = blockIdx.x;
    const int b   = bt / NBLK;
    const int n0  = (bt % NBLK) * TOK;
    const int tn  = tid & 63;
    const int q   = tid >> 6;
    const int nvalid = min(TOK, Nn - n0);

    // Phase A: load tokens tile [C][TOK], coalesced along n
    const float* tb = tokens + (size_t)b * Cc * Nn;
    #pragma unroll 4
    for (int i = 0; i < 64; ++i) {
        int c = i * 4 + q;
        float v = (tn < nvalid) ? tb[c * Nn + n0 + tn] : 0.0f;
        xs[c][tn] = v;
    }
    if (tid < nvalid) fid_s[tid] = fidx[b * Nn + n0 + tid];
    __syncthreads();

    // Phase B: per-token mean/var over C (4 partials per token)
    float s = 0.f, ss = 0.f;
    #pragma unroll 8
    for (int j = 0; j < 64; ++j) {
        float v = xs[q * 64 + j][tn];
        s += v; ss += v * v;
    }
    ps[q][tn] = s; pss[q][tn] = ss;
    __syncthreads();
    if (tid < TOK) {
        float sum = ps[0][tid] + ps[1][tid] + ps[2][tid] + ps[3][tid];
        float ssq = pss[0][tid] + pss[1][tid] + pss[2][tid] + pss[3][tid];
        float mu  = sum * (1.0f / Cc);
        float var = ssq * (1.0f / Cc) - mu * mu;
        mu_s[tid] = mu;
        rs_s[tid] = rsqrtf(var + 1e-5f);
    }
    __syncthreads();

    // Phase C: normalize + scatter (tid = channel; contiguous 1KiB atomics/token)
    const float wc = lnw[tid], bc = lnb[tid];
    float* gb = grid + (size_t)b * HWp * Cc;
    float* cb = cnt  + (size_t)b * HWp;
    for (int t = 0; t < nvalid; ++t) {
        int idx = fid_s[t];
        float xn = (xs[tid][t] - mu_s[t]) * rs_s[t] * wc + bc;
        atomicAdd(&gb[(size_t)idx * Cc + tid], xn);
        if (tid == 0) atomicAdd(&cb[idx], 1.0f);
    }
}

// ---------------- Kernel 2: cnt -> 1/max(cnt,1) ----------------
__global__ void invcnt_kernel(float* __restrict__ cnt)
{
    int i = blockIdx.x * blockDim.x + threadIdx.x;
    if (i < Bb * HWp) cnt[i] = 1.0f / fmaxf(cnt[i], 1.0f);
}

// ---------------- Kernel 3/4: depthwise 3x3, block = 1 pixel, tid = channel ----------------
template <bool FIRST>
__global__ __launch_bounds__(256) void dwconv_kernel(
    const float* __restrict__ in, const float* __restrict__ wt,
    const float* __restrict__ bias, const float* __restrict__ inv,
    const float* __restrict__ scale, float* __restrict__ out)
{
    const int tid = threadIdx.x;          // channel
    const int pix = blockIdx.x;           // b*HW + hw
    const int hw  = pix & (HWp - 1);
    const int bo  = pix >> 16;
    const int h   = hw >> 8, w = hw & 255;

    float wr[9];
    #pragma unroll
    for (int k = 0; k < 9; ++k) wr[k] = wt[tid * 9 + k];

    float acc = 0.f;
    #pragma unroll
    for (int ky = 0; ky < 3; ++ky) {
        int ih = h + ky - 1;
        if ((unsigned)ih >= (unsigned)Hh) continue;
        #pragma unroll
        for (int kx = 0; kx < 3; ++kx) {
            int iw = w + kx - 1;
            if ((unsigned)iw >= (unsigned)Ww) continue;
            int ihw = bo * HWp + ih * Ww + iw;
            float v = in[(size_t)ihw * Cc + tid];
            if (FIRST) v *= inv[ihw];          // fold scatter-mean divide into conv1 read
            acc += v * wr[ky * 3 + kx];
        }
    }
    acc += bias[tid];
    if (FIRST) acc = fmaxf(acc, 0.f);
    else       acc *= scale[tid];
    out[(size_t)pix * Cc + tid] = acc;
}

// ---------------- Kernel 5: gather + residual ----------------
__global__ __launch_bounds__(256) void gather_add_kernel(
    const float* __restrict__ tokens, const int* __restrict__ iidx,
    const float* __restrict__ g2, float* __restrict__ out)
{
    __shared__ float gs[Cc][TOK + 1];
    __shared__ int   iid_s[TOK];

    const int tid = threadIdx.x;
    const int bt  = blockIdx.x;
    const int b   = bt / NBLK;
    const int n0  = (bt % NBLK) * TOK;
    const int nvalid = min(TOK, Nn - n0);

    if (tid < nvalid) iid_s[tid] = iidx[b * Nn + n0 + tid];
    __syncthreads();

    // Phase A: fetch each token's cell vector (contiguous 1 KiB), transpose into LDS
    const float* gbase = g2 + (size_t)b * HWp * Cc;
    for (int t = 0; t < nvalid; ++t)
        gs[tid][t] = gbase[(size_t)iid_s[t] * Cc + tid];
    __syncthreads();

    // Phase B: coalesced write along n + residual
    const int tn = tid & 63, q = tid >> 6;
    const float* tb = tokens + (size_t)b * Cc * Nn;
    float* ob = out + (size_t)b * Cc * Nn;
    if (tn < nvalid) {
        #pragma unroll 4
        for (int i = 0; i < 64; ++i) {
            int c = i * 4 + q;
            ob[c * Nn + n0 + tn] = tb[c * Nn + n0 + tn] + gs[c][tn];
        }
    }
}

extern "C" void kernel_launch(void* const* d_in, const int* in_sizes, int n_in,
                              void* d_out, int out_size, void* d_ws, size_t ws_size,
                              hipStream_t stream)
{
    const float* tokens      = (const float*)d_in[0];
    const int*   flatten_idx = (const int*)  d_in[1];
    const int*   inflate_idx = (const int*)  d_in[2];
    const float* lnw         = (const float*)d_in[3];
    const float* lnb         = (const float*)d_in[4];
    const float* w1          = (const float*)d_in[5];
    const float* b1          = (const float*)d_in[6];
    const float* w2          = (const float*)d_in[7];
    const float* b2          = (const float*)d_in[8];
    const float* sw          = (const float*)d_in[9];
    float*       out         = (float*)d_out;

    char* ws = (char*)d_ws;
    const size_t gridBytes = (size_t)Bb * HWp * Cc * sizeof(float);   // 134.2 MB
    float* grid = (float*)ws;
    float* tmp  = (float*)(ws + gridBytes);
    float* cnt  = (float*)(ws + 2 * gridBytes);                       // B*HW floats

    hipMemsetAsync(grid, 0, gridBytes, stream);
    hipMemsetAsync(cnt,  0, (size_t)Bb * HWp * sizeof(float), stream);

    ln_scatter_kernel<<<Bb * NBLK, 256, 0, stream>>>(tokens, flatten_idx, lnw, lnb, grid, cnt);
    invcnt_kernel<<<(Bb * HWp + 255) / 256, 256, 0, stream>>>(cnt);
    dwconv_kernel<true ><<<Bb * HWp, 256, 0, stream>>>(grid, w1, b1, cnt, nullptr, tmp);
    dwconv_kernel<false><<<Bb * HWp, 256, 0, stream>>>(tmp,  w2, b2, nullptr, sw,  grid);
    gather_add_kernel<<<Bb * NBLK, 256, 0, stream>>>(tokens, inflate_idx, grid, out);
}

// Round 2
// 598.034 us; speedup vs baseline: 1.5152x; 1.5152x over previous
//
#include <hip/hip_runtime.h>
#include <hip/hip_fp16.h>

#define Bb   2
#define Cc   256
#define Nn   100000
#define Hh   256
#define Ww   256
#define HWp  65536
#define TOK  64
#define NBLK ((Nn + TOK - 1) / TOK)   // 1563

// ---------------- Kernel 1: LayerNorm(channel) + packed-f16 scatter-add ----------------
__global__ __launch_bounds__(256) void ln_scatter_kernel(
    const float* __restrict__ tokens, const int* __restrict__ fidx,
    const float* __restrict__ lnw, const float* __restrict__ lnb,
    __half* __restrict__ grid, float* __restrict__ cnt)
{
    __shared__ float xs[Cc][TOK + 1];      // padded: conflict-free
    __shared__ float ps[4][TOK];
    __shared__ float pss[4][TOK];
    __shared__ float mu_s[TOK], rs_s[TOK];
    __shared__ int   fid_s[TOK];

    const int tid = threadIdx.x;
    const int bt  = blockIdx.x;
    const int b   = bt / NBLK;
    const int n0  = (bt % NBLK) * TOK;
    const int tn  = tid & 63;
    const int q   = tid >> 6;
    const int nvalid = min(TOK, Nn - n0);

    // Phase A: load tokens tile [C][TOK], coalesced along n
    const float* tb = tokens + (size_t)b * Cc * Nn;
    #pragma unroll 4
    for (int i = 0; i < 64; ++i) {
        int c = i * 4 + q;
        float v = (tn < nvalid) ? tb[c * Nn + n0 + tn] : 0.0f;
        xs[c][tn] = v;
    }
    if (tid < nvalid) fid_s[tid] = fidx[b * Nn + n0 + tid];
    __syncthreads();

    // cnt atomics: 64 lanes in parallel (one per token), trivial op count
    if (tid < nvalid) atomicAdd(&cnt[(size_t)b * HWp + fid_s[tid]], 1.0f);

    // Phase B: per-token mean/var over C (4 partials per token)
    float s = 0.f, ss = 0.f;
    #pragma unroll 8
    for (int j = 0; j < 64; ++j) {
        float v = xs[q * 64 + j][tn];
        s += v; ss += v * v;
    }
    ps[q][tn] = s; pss[q][tn] = ss;
    __syncthreads();
    if (tid < TOK) {
        float sum = ps[0][tid] + ps[1][tid] + ps[2][tid] + ps[3][tid];
        float ssq = pss[0][tid] + pss[1][tid] + pss[2][tid] + pss[3][tid];
        float mu  = sum * (1.0f / Cc);
        float var = ssq * (1.0f / Cc) - mu * mu;
        mu_s[tid] = mu;
        rs_s[tid] = rsqrtf(var + 1e-5f);
    }
    __syncthreads();

    // Phase C: normalize + packed-f16 scatter.
    // tid -> (cp = channel pair 0..127, half = token parity). 2 tokens in flight.
    const int cp   = tid & 127;
    const int hlf  = tid >> 7;
    const float2 wv = *(const float2*)&lnw[2 * cp];
    const float2 bv = *(const float2*)&lnb[2 * cp];
    __half2* gb = (__half2*)grid + (size_t)b * HWp * (Cc / 2);
    for (int t = hlf; t < nvalid; t += 2) {
        const float mu = mu_s[t], rs = rs_s[t];
        float x0 = (xs[2 * cp][t]     - mu) * rs * wv.x + bv.x;
        float x1 = (xs[2 * cp + 1][t] - mu) * rs * wv.y + bv.y;
        unsafeAtomicAdd(&gb[(size_t)fid_s[t] * (Cc / 2) + cp], __floats2half2_rn(x0, x1));
    }
}

// ---------------- Kernel 2: cnt -> 1/max(cnt,1) ----------------
__global__ void invcnt_kernel(float* __restrict__ cnt)
{
    int i = blockIdx.x * blockDim.x + threadIdx.x;
    if (i < Bb * HWp) cnt[i] = 1.0f / fmaxf(cnt[i], 1.0f);
}

// ---------------- Kernel 3/4: depthwise 3x3, thread = (pixel, 4 channels) ----------------
template <bool FIRST>
__global__ __launch_bounds__(256) void dwconv_kernel(
    const __half* __restrict__ in, const float* __restrict__ wt,
    const float* __restrict__ bias, const float* __restrict__ inv,
    const float* __restrict__ scale, __half* __restrict__ out)
{
    const int idx = blockIdx.x * blockDim.x + threadIdx.x;
    const int c4  = idx & 63;             // 4-channel group
    const int pix = idx >> 6;             // b*HW + hw
    const int hw  = pix & (HWp - 1);
    const int bo  = pix >> 16;
    const int h   = hw >> 8, w = hw & 255;

    // 36 contiguous weights for channels [4c4, 4c4+4): 9 x float4, 16B-aligned
    float wr[36];
    const float4* wv = (const float4*)(wt + c4 * 36);
    #pragma unroll
    for (int i = 0; i < 9; ++i) {
        float4 qv = wv[i];
        wr[i * 4 + 0] = qv.x; wr[i * 4 + 1] = qv.y;
        wr[i * 4 + 2] = qv.z; wr[i * 4 + 3] = qv.w;
    }

    float acc0 = 0.f, acc1 = 0.f, acc2 = 0.f, acc3 = 0.f;
    #pragma unroll
    for (int ky = 0; ky < 3; ++ky) {
        int ih = h + ky - 1;
        if ((unsigned)ih >= (unsigned)Hh) continue;
        #pragma unroll
        for (int kx = 0; kx < 3; ++kx) {
            int iw = w + kx - 1;
            if ((unsigned)iw >= (unsigned)Ww) continue;
            int ihw = bo * HWp + ih * Ww + iw;
            uint2 r = *(const uint2*)(in + (size_t)ihw * Cc + c4 * 4);
            __half2 p0 = *(__half2*)&r.x, p1 = *(__half2*)&r.y;
            float2 f0 = __half22float2(p0), f1 = __half22float2(p1);
            float m = FIRST ? inv[ihw] : 1.0f;   // fold scatter-mean divide into conv1
            const int k = ky * 3 + kx;
            acc0 += f0.x * m * wr[0 * 9 + k];
            acc1 += f0.y * m * wr[1 * 9 + k];
            acc2 += f1.x * m * wr[2 * 9 + k];
            acc3 += f1.y * m * wr[3 * 9 + k];
        }
    }
    float4 bb = *(const float4*)&bias[c4 * 4];
    acc0 += bb.x; acc1 += bb.y; acc2 += bb.z; acc3 += bb.w;
    if (FIRST) {
        acc0 = fmaxf(acc0, 0.f); acc1 = fmaxf(acc1, 0.f);
        acc2 = fmaxf(acc2, 0.f); acc3 = fmaxf(acc3, 0.f);
    } else {
        float4 sv = *(const float4*)&scale[c4 * 4];
        acc0 *= sv.x; acc1 *= sv.y; acc2 *= sv.z; acc3 *= sv.w;
    }
    __half2 o0 = __floats2half2_rn(acc0, acc1);
    __half2 o1 = __floats2half2_rn(acc2, acc3);
    uint2 o; o.x = *(unsigned int*)&o0; o.y = *(unsigned int*)&o1;
    *(uint2*)(out + (size_t)pix * Cc + c4 * 4) = o;
}

// ---------------- Kernel 5: gather + residual ----------------
__global__ __launch_bounds__(256) void gather_add_kernel(
    const float* __restrict__ tokens, const int* __restrict__ iidx,
    const __half* __restrict__ g2, float* __restrict__ out)
{
    __shared__ float gs[Cc][TOK + 1];
    __shared__ int   iid_s[TOK];

    const int tid = threadIdx.x;
    const int bt  = blockIdx.x;
    const int b   = bt / NBLK;
    const int n0  = (bt % NBLK) * TOK;
    const int nvalid = min(TOK, Nn - n0);

    if (tid < nvalid) iid_s[tid] = iidx[b * Nn + n0 + tid];
    __syncthreads();

    // Phase A: fetch cell vectors (8B/lane, contiguous 512B per token), 4 tokens in flight
    const int tq = tid >> 6;     // token sub-slot
    const int c4 = tid & 63;     // 4-channel group
    const __half* gbase = g2 + (size_t)b * HWp * Cc;
    for (int t0 = 0; t0 < TOK; t0 += 4) {
        int t = t0 + tq;
        if (t < nvalid) {
            uint2 r = *(const uint2*)(gbase + (size_t)iid_s[t] * Cc + c4 * 4);
            __half2 p0 = *(__half2*)&r.x, p1 = *(__half2*)&r.y;
            float2 f0 = __half22float2(p0), f1 = __half22float2(p1);
            gs[c4 * 4 + 0][t] = f0.x;
            gs[c4 * 4 + 1][t] = f0.y;
            gs[c4 * 4 + 2][t] = f1.x;
            gs[c4 * 4 + 3][t] = f1.y;
        }
    }
    __syncthreads();

    // Phase B: coalesced write along n + residual
    const int tn = tid & 63, q = tid >> 6;
    const float* tb = tokens + (size_t)b * Cc * Nn;
    float* ob = out + (size_t)b * Cc * Nn;
    if (tn < nvalid) {
        #pragma unroll 4
        for (int i = 0; i < 64; ++i) {
            int c = i * 4 + q;
            ob[c * Nn + n0 + tn] = tb[c * Nn + n0 + tn] + gs[c][tn];
        }
    }
}

extern "C" void kernel_launch(void* const* d_in, const int* in_sizes, int n_in,
                              void* d_out, int out_size, void* d_ws, size_t ws_size,
                              hipStream_t stream)
{
    const float* tokens      = (const float*)d_in[0];
    const int*   flatten_idx = (const int*)  d_in[1];
    const int*   inflate_idx = (const int*)  d_in[2];
    const float* lnw         = (const float*)d_in[3];
    const float* lnb         = (const float*)d_in[4];
    const float* w1          = (const float*)d_in[5];
    const float* b1          = (const float*)d_in[6];
    const float* w2          = (const float*)d_in[7];
    const float* b2          = (const float*)d_in[8];
    const float* sw          = (const float*)d_in[9];
    float*       out         = (float*)d_out;

    char* ws = (char*)d_ws;
    const size_t gridBytes = (size_t)Bb * HWp * Cc * sizeof(__half);  // 64 MiB
    __half* grid = (__half*)ws;
    __half* tmp  = (__half*)(ws + gridBytes);
    float*  cnt  = (float*)(ws + 2 * gridBytes);                      // B*HW f32

    hipMemsetAsync(grid, 0, gridBytes, stream);
    hipMemsetAsync(cnt,  0, (size_t)Bb * HWp * sizeof(float), stream);

    ln_scatter_kernel<<<Bb * NBLK, 256, 0, stream>>>(tokens, flatten_idx, lnw, lnb, grid, cnt);
    invcnt_kernel<<<(Bb * HWp + 255) / 256, 256, 0, stream>>>(cnt);
    dwconv_kernel<true ><<<(Bb * HWp * 64) / 256, 256, 0, stream>>>(grid, w1, b1, cnt, nullptr, tmp);
    dwconv_kernel<false><<<(Bb * HWp * 64) / 256, 256, 0, stream>>>(tmp,  w2, b2, nullptr, sw,  grid);
    gather_add_kernel<<<Bb * NBLK, 256, 0, stream>>>(tokens, inflate_idx, grid, out);
}

// Round 3
// 526.291 us; speedup vs baseline: 1.7218x; 1.1363x over previous
//
#include <hip/hip_runtime.h>
#include <hip/hip_fp16.h>

#define Bb   2
#define Cc   256
#define Nn   100000
#define Hh   256
#define Ww   256
#define HWp  65536
#define TOK  64
#define NBLK ((Nn + TOK - 1) / TOK)   // 1563

// ---------------- Kernel 1: LayerNorm(channel) + packed-f16 scatter-add ----------------
// LDS ~36 KB -> 4 blocks/CU (~50% occupancy) to hide atomic latency.
__global__ __launch_bounds__(256) void ln_scatter_kernel(
    const float* __restrict__ tokens, const int* __restrict__ fidx,
    const float* __restrict__ lnw, const float* __restrict__ lnb,
    __half* __restrict__ grid, float* __restrict__ cnt)
{
    __shared__ __half2 xs[128][TOK + 1];   // [channel-pair][token], banks (cp+t)%32
    __shared__ float  ps[4][TOK];
    __shared__ float  pss[4][TOK];
    __shared__ float2 ms_s[TOK];           // (mu, rsqrt)
    __shared__ int    fid_s[TOK];

    const int tid = threadIdx.x;
    const int bt  = blockIdx.x;
    const int b   = bt / NBLK;
    const int n0  = (bt % NBLK) * TOK;
    const int tn  = tid & 63;
    const int q   = tid >> 6;
    const int nvalid = min(TOK, Nn - n0);

    // Phase A: load tokens tile [C][TOK] coalesced along n; accumulate stats inline.
    const float* tb = tokens + (size_t)b * Cc * Nn;
    __half* xsh = (__half*)&xs[0][0];
    float s = 0.f, ss = 0.f;
    #pragma unroll 8
    for (int i = 0; i < 64; ++i) {
        int c = i * 4 + q;
        float v = (tn < nvalid) ? tb[c * Nn + n0 + tn] : 0.0f;
        s += v; ss += v * v;
        // element (c, t): half index (c>>1)*(2*(TOK+1)) + 2*t + (c&1); lanes stride 2 halves -> conflict-free
        xsh[(c >> 1) * (2 * (TOK + 1)) + 2 * tn + (c & 1)] = __float2half(v);
    }
    ps[q][tn] = s; pss[q][tn] = ss;
    if (tid < nvalid) fid_s[tid] = fidx[b * Nn + n0 + tid];
    __syncthreads();

    // cnt atomics: 64 lanes in parallel
    if (tid < nvalid) atomicAdd(&cnt[(size_t)b * HWp + fid_s[tid]], 1.0f);

    if (tid < TOK) {
        float sum = ps[0][tid] + ps[1][tid] + ps[2][tid] + ps[3][tid];
        float ssq = pss[0][tid] + pss[1][tid] + pss[2][tid] + pss[3][tid];
        float mu  = sum * (1.0f / Cc);
        float var = ssq * (1.0f / Cc) - mu * mu;
        ms_s[tid] = make_float2(mu, rsqrtf(var + 1e-5f));
    }
    __syncthreads();

    // Phase C: normalize + packed-f16 scatter. lane -> (cp 0..127, token parity)
    const int cp  = tid & 127;
    const int hlf = tid >> 7;
    const float2 wv = *(const float2*)&lnw[2 * cp];
    const float2 bv = *(const float2*)&lnb[2 * cp];
    __half2* gb = (__half2*)grid + (size_t)b * HWp * (Cc / 2);
    for (int t = hlf; t < nvalid; t += 2) {
        float2 mr = ms_s[t];
        float2 xf = __half22float2(xs[cp][t]);
        float x0 = (xf.x - mr.x) * mr.y * wv.x + bv.x;
        float x1 = (xf.y - mr.x) * mr.y * wv.y + bv.y;
        unsafeAtomicAdd(&gb[(size_t)fid_s[t] * (Cc / 2) + cp], __floats2half2_rn(x0, x1));
    }
}

// ---------------- Kernel 2/3: depthwise 3x3, thread = (pixel, 4 channels) ----------------
template <bool FIRST>
__global__ __launch_bounds__(256) void dwconv_kernel(
    const __half* __restrict__ in, const float* __restrict__ wt,
    const float* __restrict__ bias, const float* __restrict__ cnt,
    const float* __restrict__ scale, __half* __restrict__ out)
{
    const int idx = blockIdx.x * blockDim.x + threadIdx.x;
    const int c4  = idx & 63;             // 4-channel group
    const int pix = idx >> 6;             // b*HW + hw
    const int hw  = pix & (HWp - 1);
    const int bo  = pix >> 16;
    const int h   = hw >> 8, w = hw & 255;

    float wr[36];
    const float4* wv = (const float4*)(wt + c4 * 36);
    #pragma unroll
    for (int i = 0; i < 9; ++i) {
        float4 qv = wv[i];
        wr[i * 4 + 0] = qv.x; wr[i * 4 + 1] = qv.y;
        wr[i * 4 + 2] = qv.z; wr[i * 4 + 3] = qv.w;
    }

    float acc0 = 0.f, acc1 = 0.f, acc2 = 0.f, acc3 = 0.f;
    #pragma unroll
    for (int ky = 0; ky < 3; ++ky) {
        int ih = h + ky - 1;
        if ((unsigned)ih >= (unsigned)Hh) continue;
        #pragma unroll
        for (int kx = 0; kx < 3; ++kx) {
            int iw = w + kx - 1;
            if ((unsigned)iw >= (unsigned)Ww) continue;
            int ihw = bo * HWp + ih * Ww + iw;
            uint2 r = *(const uint2*)(in + (size_t)ihw * Cc + c4 * 4);
            __half2 p0 = *(__half2*)&r.x, p1 = *(__half2*)&r.y;
            float2 f0 = __half22float2(p0), f1 = __half22float2(p1);
            float m = FIRST ? (1.0f / fmaxf(cnt[ihw], 1.0f)) : 1.0f;  // fused scatter-mean divide
            const int k = ky * 3 + kx;
            acc0 += f0.x * m * wr[0 * 9 + k];
            acc1 += f0.y * m * wr[1 * 9 + k];
            acc2 += f1.x * m * wr[2 * 9 + k];
            acc3 += f1.y * m * wr[3 * 9 + k];
        }
    }
    float4 bb = *(const float4*)&bias[c4 * 4];
    acc0 += bb.x; acc1 += bb.y; acc2 += bb.z; acc3 += bb.w;
    if (FIRST) {
        acc0 = fmaxf(acc0, 0.f); acc1 = fmaxf(acc1, 0.f);
        acc2 = fmaxf(acc2, 0.f); acc3 = fmaxf(acc3, 0.f);
    } else {
        float4 sv = *(const float4*)&scale[c4 * 4];
        acc0 *= sv.x; acc1 *= sv.y; acc2 *= sv.z; acc3 *= sv.w;
    }
    __half2 o0 = __floats2half2_rn(acc0, acc1);
    __half2 o1 = __floats2half2_rn(acc2, acc3);
    uint2 o; o.x = *(unsigned int*)&o0; o.y = *(unsigned int*)&o1;
    *(uint2*)(out + (size_t)pix * Cc + c4 * 4) = o;
}

// ---------------- Kernel 4: gather + residual ----------------
__global__ __launch_bounds__(256) void gather_add_kernel(
    const float* __restrict__ tokens, const int* __restrict__ iidx,
    const __half* __restrict__ g2, float* __restrict__ out)
{
    __shared__ float gs[Cc][TOK + 1];
    __shared__ int   iid_s[TOK];

    const int tid = threadIdx.x;
    const int bt  = blockIdx.x;
    const int b   = bt / NBLK;
    const int n0  = (bt % NBLK) * TOK;
    const int nvalid = min(TOK, Nn - n0);

    if (tid < nvalid) iid_s[tid] = iidx[b * Nn + n0 + tid];
    __syncthreads();

    // Phase A: fetch cell vectors (8B/lane, 512B per token), 4 tokens in flight
    const int tq = tid >> 6;
    const int c4 = tid & 63;
    const __half* gbase = g2 + (size_t)b * HWp * Cc;
    for (int t0 = 0; t0 < TOK; t0 += 4) {
        int t = t0 + tq;
        if (t < nvalid) {
            uint2 r = *(const uint2*)(gbase + (size_t)iid_s[t] * Cc + c4 * 4);
            __half2 p0 = *(__half2*)&r.x, p1 = *(__half2*)&r.y;
            float2 f0 = __half22float2(p0), f1 = __half22float2(p1);
            gs[c4 * 4 + 0][t] = f0.x;
            gs[c4 * 4 + 1][t] = f0.y;
            gs[c4 * 4 + 2][t] = f1.x;
            gs[c4 * 4 + 3][t] = f1.y;
        }
    }
    __syncthreads();

    // Phase B: coalesced write along n + residual
    const int tn = tid & 63, q = tid >> 6;
    const float* tb = tokens + (size_t)b * Cc * Nn;
    float* ob = out + (size_t)b * Cc * Nn;
    if (tn < nvalid) {
        #pragma unroll 4
        for (int i = 0; i < 64; ++i) {
            int c = i * 4 + q;
            ob[c * Nn + n0 + tn] = tb[c * Nn + n0 + tn] + gs[c][tn];
        }
    }
}

extern "C" void kernel_launch(void* const* d_in, const int* in_sizes, int n_in,
                              void* d_out, int out_size, void* d_ws, size_t ws_size,
                              hipStream_t stream)
{
    const float* tokens      = (const float*)d_in[0];
    const int*   flatten_idx = (const int*)  d_in[1];
    const int*   inflate_idx = (const int*)  d_in[2];
    const float* lnw         = (const float*)d_in[3];
    const float* lnb         = (const float*)d_in[4];
    const float* w1          = (const float*)d_in[5];
    const float* b1          = (const float*)d_in[6];
    const float* w2          = (const float*)d_in[7];
    const float* b2          = (const float*)d_in[8];
    const float* sw          = (const float*)d_in[9];
    float*       out         = (float*)d_out;

    char* ws = (char*)d_ws;
    const size_t gridBytes = (size_t)Bb * HWp * Cc * sizeof(__half);  // 64 MiB
    __half* grid = (__half*)ws;
    __half* tmp  = (__half*)(ws + gridBytes);
    float*  cnt  = (float*)(ws + 2 * gridBytes);                      // B*HW f32

    hipMemsetAsync(grid, 0, gridBytes, stream);
    hipMemsetAsync(cnt,  0, (size_t)Bb * HWp * sizeof(float), stream);

    ln_scatter_kernel<<<Bb * NBLK, 256, 0, stream>>>(tokens, flatten_idx, lnw, lnb, grid, cnt);
    dwconv_kernel<true ><<<(Bb * HWp * 64) / 256, 256, 0, stream>>>(grid, w1, b1, cnt, nullptr, tmp);
    dwconv_kernel<false><<<(Bb * HWp * 64) / 256, 256, 0, stream>>>(tmp,  w2, b2, nullptr, sw,  grid);
    gather_add_kernel<<<Bb * NBLK, 256, 0, stream>>>(tokens, inflate_idx, grid, out);
}